// Round 2
// baseline (352.114 us; speedup 1.0000x reference)
//
#include <hip/hip_runtime.h>
#include <stdint.h>

#define NNODES 100000
#define NEDGES 100000
#define DIM    256
#define NCH    4          // 2 side + 2 rel
#define ET     64         // edges per block, 4 waves, each wave: all 4 M-tiles x 4 f-tiles
#define RSF    264        // fp16 per staged row (256 + 8 pad; 264*2B=528B)
#define CONVB  2048       // grid-stride conversion blocks

typedef _Float16 f16x8 __attribute__((ext_vector_type(8)));
typedef _Float16 f16x4 __attribute__((ext_vector_type(4)));
typedef float f32x4  __attribute__((ext_vector_type(4)));

// ---------------------------------------------------------------------------
// Fused prep (single launch):
//  blocks [0,128): build the 4 fused/transposed channel matrices in MFMA
//    B-fragment order, split into fp16 hi/lo (22-bit effective).
//  blocks [128, 128+CONVB): convert h (f32, 102.4 MB) -> fp16 (51.2 MB),
//    dense grid-stride, 2 loads in flight.
// ---------------------------------------------------------------------------
__global__ void prep_fused(const float* __restrict__ RW,
                           const float* __restrict__ dside,
                           const float* __restrict__ Wrel,
                           const float* __restrict__ h,
                           _Float16* __restrict__ Bh, _Float16* __restrict__ Bl,
                           _Float16* __restrict__ H16) {
    if (blockIdx.x < 128) {
        int t = blockIdx.x * blockDim.x + threadIdx.x;   // < 32768
        int lane = t & 63;
        int ft   = (t >> 6) & 15;
        int kc   = (t >> 10) & 7;
        int c    = t >> 13;
        int quad = lane >> 4, col = lane & 15;
        int f     = ft * 16 + col;
        int kbase = kc * 32 + quad * 8;

        f16x8 vh, vl;
#pragma unroll
        for (int j = 0; j < 8; ++j) {
            int k = kbase + j;
            float val;
            if (c < 2) {
                val = dside[c * DIM + f] * RW[f * DIM + k] * dside[c * DIM + k];
            } else {
                val = Wrel[(size_t)(c - 2) * DIM * DIM + f * DIM + k];
            }
            _Float16 hi = (_Float16)val;
            vh[j] = hi;
            vl[j] = (_Float16)(val - (float)hi);
        }
        ((f16x8*)Bh)[t] = vh;
        ((f16x8*)Bl)[t] = vl;
    } else {
        const int total4 = NNODES * DIM / 4;   // 6.4e6 f32x4 chunks
        const int stride = CONVB * 256;
        int i = (blockIdx.x - 128) * 256 + (int)threadIdx.x;
        const f32x4* s4 = (const f32x4*)h;
        f16x4* d4 = (f16x4*)H16;
        for (; i + stride < total4; i += 2 * stride) {
            f32x4 a = s4[i];
            f32x4 b = s4[i + stride];
            f16x4 oa, ob;
#pragma unroll
            for (int j = 0; j < 4; ++j) { oa[j] = (_Float16)a[j]; ob[j] = (_Float16)b[j]; }
            d4[i] = oa; d4[i + stride] = ob;
        }
        if (i < total4) {
            f32x4 a = s4[i];
            f16x4 o;
#pragma unroll
            for (int j = 0; j < 4; ++j) o[j] = (_Float16)a[j];
            d4[i] = o;
        }
    }
}

// ---------------------------------------------------------------------------
// Edge kernel v3: barrier-free K-loop, NO LDS staging of A.
//  - A fragments gathered DIRECTLY from global H16 in MFMA layout:
//    lane(quad,col) loads 16B at H16[src[e0+mt*16+col]*256 + kc*32 + quad*8].
//    H16 (51 MB) is fully L3-resident; this kills the A LDS round-trip,
//    its bank conflicts, its 4-8x redundant ds_reads, and ALL mid-kernel
//    barriers (round-1 lesson: LDS A-redundancy, not B L2 traffic, was
//    the regression driver).
//  - 4 waves/block, wave w owns f-tiles {4w..4w+3} and ALL 4 M-tiles
//    (64 edges): B slice read once per block (256 KB) -> 1.6 GB total,
//    half the 169us baseline's 3.2 GB.
//  - V rows prefetched into regs at wave start (latency hides under 256
//    MFMAs), written to LDS after the K-loop purely for the f-transpose.
//    Only 2 barriers, both at the tail.
//  - acc 64 VGPR + A 32 + vR 32 + B in flight: ~200 VGPR, 2 blocks/CU.
//    Waves are phase-independent so low occupancy is acceptable.
// ---------------------------------------------------------------------------
__global__ __launch_bounds__(256, 2)
void edge_kernel(const _Float16* __restrict__ H16,
                 const int* __restrict__ src_idx,
                 const int* __restrict__ dst_idx,
                 const float* __restrict__ brel,
                 const _Float16* __restrict__ Bh_sw,
                 const _Float16* __restrict__ Bl_sw,
                 float* __restrict__ out) {
    const int c    = blockIdx.y;
    const int e0   = blockIdx.x * ET;
    const int tid  = threadIdx.x;
    const int w    = tid >> 6;          // 0..3
    const int lane = tid & 63;
    const int quad = lane >> 4, col = lane & 15;

    __shared__ __align__(16) _Float16 s_v[ET * RSF];   // 33,792 B
    __shared__ float red[4][ET];                       // 1 KB

    // ---- Prefetch V rows (wave w owns rows w*16..w*16+15) into registers ----
    f16x4 vR[16];
#pragma unroll
    for (int i = 0; i < 16; ++i) {
        int e = e0 + w * 16 + i;
        if (e >= NEDGES) e = NEDGES - 1;
        int di = dst_idx[(size_t)c * NEDGES + e];     // wave-uniform broadcast load
        vR[i] = *(const f16x4*)(H16 + (size_t)di * DIM + lane * 4);
    }

    // ---- A row base pointers (per-lane: row = mt*16 + col) ----
    const _Float16* abase[4];
#pragma unroll
    for (int mt = 0; mt < 4; ++mt) {
        int e = e0 + mt * 16 + col;
        if (e >= NEDGES) e = NEDGES - 1;
        int si = src_idx[(size_t)c * NEDGES + e];
        abase[mt] = H16 + (size_t)si * DIM + quad * 8;
    }

    // ---- Barrier-free K-loop: A direct-gather, B hi/lo from L2 table ----
    f32x4 acc[4][4];   // [mt][ftl]
#pragma unroll
    for (int mt = 0; mt < 4; ++mt)
#pragma unroll
        for (int ftl = 0; ftl < 4; ++ftl) acc[mt][ftl] = (f32x4){0.f, 0.f, 0.f, 0.f};

    const f16x8* Bp_h = (const f16x8*)Bh_sw + ((size_t)(c * 8) * 16 + w * 4) * 64 + lane;
    const f16x8* Bp_l = (const f16x8*)Bl_sw + ((size_t)(c * 8) * 16 + w * 4) * 64 + lane;

#pragma unroll
    for (int kc = 0; kc < 8; ++kc) {
        f16x8 A[4];
#pragma unroll
        for (int mt = 0; mt < 4; ++mt)
            A[mt] = *(const f16x8*)(abase[mt] + kc * 32);

#pragma unroll
        for (int ftl = 0; ftl < 4; ++ftl) {
            f16x8 bh = Bp_h[kc * 1024 + ftl * 64];
            f16x8 bl = Bp_l[kc * 1024 + ftl * 64];
#pragma unroll
            for (int mt = 0; mt < 4; ++mt) {
                acc[mt][ftl] = __builtin_amdgcn_mfma_f32_16x16x32_f16(A[mt], bh, acc[mt][ftl], 0, 0, 0);
                acc[mt][ftl] = __builtin_amdgcn_mfma_f32_16x16x32_f16(A[mt], bl, acc[mt][ftl], 0, 0, 0);
            }
        }
    }

    // ---- Stage V to LDS (only use of LDS besides reduction) ----
#pragma unroll
    for (int i = 0; i < 16; ++i) {
        int lr = w * 16 + i;
        *(f16x4*)&s_v[lr * RSF + lane * 4] = vR[i];
    }
    __syncthreads();

    // ---- Epilogue: score_e = sum_f (C[e][f] + bias[f]) * V[e][f] ----
    // C/D layout: row(e) = quad*4 + r, col(f) = lane&15; f = (w*4+ftl)*16+col.
    float bias[4];
#pragma unroll
    for (int ftl = 0; ftl < 4; ++ftl) {
        int f = (w * 4 + ftl) * 16 + col;
        bias[ftl] = (c >= 2) ? brel[(size_t)(c - 2) * DIM + f] : 0.f;
    }

    float psum[4][4];  // [mt][r]
#pragma unroll
    for (int mt = 0; mt < 4; ++mt) {
#pragma unroll
        for (int r = 0; r < 4; ++r) {
            int el = mt * 16 + quad * 4 + r;
            float s = 0.f;
#pragma unroll
            for (int ftl = 0; ftl < 4; ++ftl) {
                int f = (w * 4 + ftl) * 16 + col;
                float v = (float)s_v[el * RSF + f];
                s += (acc[mt][ftl][r] + bias[ftl]) * v;
            }
            psum[mt][r] = s;
        }
    }

    // Reduce across the 16 f-columns (xor lane bits 0..3)
#pragma unroll
    for (int off = 1; off < 16; off <<= 1) {
#pragma unroll
        for (int mt = 0; mt < 4; ++mt)
#pragma unroll
            for (int r = 0; r < 4; ++r)
                psum[mt][r] += __shfl_xor(psum[mt][r], off, 64);
    }
    if (col == 0) {
#pragma unroll
        for (int mt = 0; mt < 4; ++mt)
#pragma unroll
            for (int r = 0; r < 4; ++r)
                red[w][mt * 16 + quad * 4 + r] = psum[mt][r];
    }
    __syncthreads();

    if (tid < ET) {
        int idx = e0 + tid;
        if (idx < NEDGES) {
            float s = red[0][tid] + red[1][tid] + red[2][tid] + red[3][tid];
            out[(size_t)c * NEDGES + idx] = s;
        }
    }
}

extern "C" void kernel_launch(void* const* d_in, const int* in_sizes, int n_in,
                              void* d_out, int out_size, void* d_ws, size_t ws_size,
                              hipStream_t stream) {
    const float* hmat  = (const float*)d_in[0];
    const int*   src   = (const int*)d_in[1];
    const int*   dst   = (const int*)d_in[2];
    const float* RW    = (const float*)d_in[3];
    const float* dside = (const float*)d_in[4];
    const float* Wrel  = (const float*)d_in[5];
    const float* brel  = (const float*)d_in[6];
    float* out = (float*)d_out;

    // Workspace: Bh (512 KB) | Bl (512 KB) | H16 (51.2 MB)
    const size_t nB = (size_t)NCH * DIM * DIM;   // fp16 per table
    _Float16* Bh  = (_Float16*)d_ws;
    _Float16* Bl  = Bh + nB;
    _Float16* H16 = Bl + nB;

    prep_fused<<<dim3(128 + CONVB), dim3(256), 0, stream>>>(
        RW, dside, Wrel, hmat, Bh, Bl, H16);

    dim3 grid((NEDGES + ET - 1) / ET, NCH);
    edge_kernel<<<grid, dim3(256), 0, stream>>>(H16, src, dst, brel, Bh, Bl, out);
}

// Round 3
// 300.765 us; speedup vs baseline: 1.1707x; 1.1707x over previous
//
#include <hip/hip_runtime.h>
#include <stdint.h>

#define NNODES 100000
#define NEDGES 100000
#define DIM    256
#define NCH    4          // 2 side + 2 rel
#define ET     64         // edges per tile
#define NT     1563       // ceil(NEDGES / ET)
#define NBX    64         // blocks per channel; each block strides tiles by NBX
#define RSF    264        // fp16 per staged row (256 + 8 pad -> conflict-benign)
#define CONVB  2048       // grid-stride conversion blocks

typedef _Float16 f16x8 __attribute__((ext_vector_type(8)));
typedef _Float16 f16x4 __attribute__((ext_vector_type(4)));
typedef float f32x4  __attribute__((ext_vector_type(4)));

// ---------------------------------------------------------------------------
// Fused prep (single launch): B tables (hi/lo fp16, MFMA B-fragment order)
// + h f32 -> fp16 conversion. Unchanged from previous rounds.
// ---------------------------------------------------------------------------
__global__ void prep_fused(const float* __restrict__ RW,
                           const float* __restrict__ dside,
                           const float* __restrict__ Wrel,
                           const float* __restrict__ h,
                           _Float16* __restrict__ Bh, _Float16* __restrict__ Bl,
                           _Float16* __restrict__ H16) {
    if (blockIdx.x < 128) {
        int t = blockIdx.x * blockDim.x + threadIdx.x;   // < 32768
        int lane = t & 63;
        int ft   = (t >> 6) & 15;
        int kc   = (t >> 10) & 7;
        int c    = t >> 13;
        int quad = lane >> 4, col = lane & 15;
        int f     = ft * 16 + col;
        int kbase = kc * 32 + quad * 8;

        f16x8 vh, vl;
#pragma unroll
        for (int j = 0; j < 8; ++j) {
            int k = kbase + j;
            float val;
            if (c < 2) {
                val = dside[c * DIM + f] * RW[f * DIM + k] * dside[c * DIM + k];
            } else {
                val = Wrel[(size_t)(c - 2) * DIM * DIM + f * DIM + k];
            }
            _Float16 hi = (_Float16)val;
            vh[j] = hi;
            vl[j] = (_Float16)(val - (float)hi);
        }
        ((f16x8*)Bh)[t] = vh;
        ((f16x8*)Bl)[t] = vl;
    } else {
        const int total4 = NNODES * DIM / 4;   // 6.4e6 f32x4 chunks
        const int stride = CONVB * 256;
        int i = (blockIdx.x - 128) * 256 + (int)threadIdx.x;
        const f32x4* s4 = (const f32x4*)h;
        f16x4* d4 = (f16x4*)H16;
        for (; i + stride < total4; i += 2 * stride) {
            f32x4 a = s4[i];
            f32x4 b = s4[i + stride];
            f16x4 oa, ob;
#pragma unroll
            for (int j = 0; j < 4; ++j) { oa[j] = (_Float16)a[j]; ob[j] = (_Float16)b[j]; }
            d4[i] = oa; d4[i + stride] = ob;
        }
        if (i < total4) {
            f32x4 a = s4[i];
            f16x4 o;
#pragma unroll
            for (int j = 0; j < 4; ++j) o[j] = (_Float16)a[j];
            d4[i] = o;
        }
    }
}

// ---------------------------------------------------------------------------
// Edge kernel v4: register-resident B, tile-looped edges (persistent-ish).
//  - 256 blocks total (64 x 4ch), 512 threads (8 waves), ~1 block/CU.
//  - Wave w owns f-tiles {2w,2w+1}: B hi/lo for 8 kc = 32 f16x8 = 128 VGPR,
//    loaded ONCE per block. B L2 traffic: 3.2 GB (round-0) -> 64 MB.
//  - Each block loops ~24-25 tiles of 64 edges. Per tile: round-0-style LDS
//    A/V staging (proven layout/fragments) + 128 dual-term MFMAs per wave.
//  - T14 pipeline: row gathers for tile t+1 issued right after the stage
//    barrier (consumed next tile, ~5000cy later); index packs loaded 2 tiles
//    ahead (1 VGPR per stage via lane-packed idx + __shfl redistribution).
//  - 2 barriers per tile. VGPR budget ~240 (B 128 + acc 32 + pA/pV 32 +
//    A-frags 16 + misc) -> 2 waves/SIMD; latency hidden by pipelining, not
//    occupancy.
// ---------------------------------------------------------------------------
__global__ __launch_bounds__(512, 2)
void edge_kernel(const _Float16* __restrict__ H16,
                 const int* __restrict__ src_idx,
                 const int* __restrict__ dst_idx,
                 const float* __restrict__ brel,
                 const _Float16* __restrict__ Bh_sw,
                 const _Float16* __restrict__ Bl_sw,
                 float* __restrict__ out) {
    const int c    = blockIdx.y;
    const int tid  = threadIdx.x;
    const int w    = tid >> 6;          // 0..7
    const int lane = tid & 63;
    const int quad = lane >> 4, col = lane & 15;

    __shared__ __align__(16) _Float16 s_a[ET * RSF];   // 33,792 B
    __shared__ __align__(16) _Float16 s_v[ET * RSF];   // 33,792 B
    __shared__ float red[8][ET];                       // 2 KB

    // ---- B registers: wave w holds ft = {2w, 2w+1}, all kc, hi+lo ----
    f16x8 Bh_r[8][2], Bl_r[8][2];
    {
        const f16x8* bh = (const f16x8*)Bh_sw;
        const f16x8* bl = (const f16x8*)Bl_sw;
#pragma unroll
        for (int kc = 0; kc < 8; ++kc)
#pragma unroll
            for (int ftl = 0; ftl < 2; ++ftl) {
                int o = ((c * 8 + kc) * 16 + (w * 2 + ftl)) * 64 + lane;
                Bh_r[kc][ftl] = bh[o];
                Bl_r[kc][ftl] = bl[o];
            }
    }
    float bias[2];
#pragma unroll
    for (int ftl = 0; ftl < 2; ++ftl) {
        int f = (w * 2 + ftl) * 16 + col;
        bias[ftl] = (c >= 2) ? brel[(size_t)(c - 2) * DIM + f] : 0.f;
    }

    // Lane-packed index loads: lanes 0..7 -> src idx of rows w*8+0..7,
    // lanes 8..15 -> dst idx (pattern repeats harmlessly for lanes >= 16).
    const int  j8   = lane & 7;
    const bool isV  = (lane & 8) != 0;
    const int* ibase = (isV ? dst_idx : src_idx) + (size_t)c * NEDGES;

    auto loadpack = [&](int t) -> int {
        int e = t * ET + w * 8 + j8;
        if (e >= NEDGES) e = NEDGES - 1;
        return ibase[e];
    };

    // ---- Prologue: gather tile t0 rows; preload idx pack for t0+NBX ----
    const int t0 = blockIdx.x;
    f16x4 pA[8], pV[8];
    {
        int ip = loadpack(t0);
#pragma unroll
        for (int i = 0; i < 8; ++i) {
            int ia = __shfl(ip, i, 64);
            int iv = __shfl(ip, 8 + i, 64);
            pA[i] = *(const f16x4*)(H16 + (size_t)ia * DIM + lane * 4);
            pV[i] = *(const f16x4*)(H16 + (size_t)iv * DIM + lane * 4);
        }
    }
    int ipk0 = 0, ipk1 = 0;
    if (t0 + NBX < NT) ipk1 = loadpack(t0 + NBX);

    // ---- Tile body (inlined lambda; ipkUse = idx for t+NBX, ipkLoad ----
    // ---- receives idx for t+2*NBX). Parity alternates the two packs. ----
    auto body = [&](int t, int& ipkUse, int& ipkLoad) {
        // stage tile t rows (gathered during previous tile)
#pragma unroll
        for (int i = 0; i < 8; ++i) {
            int lr = w * 8 + i;
            *(f16x4*)&s_a[lr * RSF + lane * 4] = pA[i];
            *(f16x4*)&s_v[lr * RSF + lane * 4] = pV[i];
        }
        __syncthreads();

        // issue idx loads 2 tiles ahead, row gathers 1 tile ahead (T14)
        if (t + 2 * NBX < NT) ipkLoad = loadpack(t + 2 * NBX);
        if (t + NBX < NT) {
#pragma unroll
            for (int i = 0; i < 8; ++i) {
                int ia = __shfl(ipkUse, i, 64);
                int iv = __shfl(ipkUse, 8 + i, 64);
                pA[i] = *(const f16x4*)(H16 + (size_t)ia * DIM + lane * 4);
                pV[i] = *(const f16x4*)(H16 + (size_t)iv * DIM + lane * 4);
            }
        }

        // K-loop: A from LDS, B from registers, 2-term f16 MFMA
        f32x4 acc[4][2];
#pragma unroll
        for (int mt = 0; mt < 4; ++mt)
#pragma unroll
            for (int ftl = 0; ftl < 2; ++ftl) acc[mt][ftl] = (f32x4){0.f, 0.f, 0.f, 0.f};

#pragma unroll
        for (int kc = 0; kc < 8; ++kc) {
            f16x8 A[4];
#pragma unroll
            for (int mt = 0; mt < 4; ++mt)
                A[mt] = *(const f16x8*)&s_a[(mt * 16 + col) * RSF + kc * 32 + quad * 8];
#pragma unroll
            for (int ftl = 0; ftl < 2; ++ftl)
#pragma unroll
                for (int mt = 0; mt < 4; ++mt) {
                    acc[mt][ftl] = __builtin_amdgcn_mfma_f32_16x16x32_f16(A[mt], Bh_r[kc][ftl], acc[mt][ftl], 0, 0, 0);
                    acc[mt][ftl] = __builtin_amdgcn_mfma_f32_16x16x32_f16(A[mt], Bl_r[kc][ftl], acc[mt][ftl], 0, 0, 0);
                }
        }

        // Epilogue: score_e = sum_f (C[e][f] + bias[f]) * V[e][f]
        float psum[4][4];
#pragma unroll
        for (int mt = 0; mt < 4; ++mt) {
#pragma unroll
            for (int r = 0; r < 4; ++r) {
                int el = mt * 16 + quad * 4 + r;
                float s = 0.f;
#pragma unroll
                for (int ftl = 0; ftl < 2; ++ftl) {
                    int f = (w * 2 + ftl) * 16 + col;
                    float v = (float)s_v[el * RSF + f];
                    s += (acc[mt][ftl][r] + bias[ftl]) * v;
                }
                psum[mt][r] = s;
            }
        }
#pragma unroll
        for (int off = 1; off < 16; off <<= 1) {
#pragma unroll
            for (int mt = 0; mt < 4; ++mt)
#pragma unroll
                for (int r = 0; r < 4; ++r)
                    psum[mt][r] += __shfl_xor(psum[mt][r], off, 64);
        }
        if (col == 0) {
#pragma unroll
            for (int mt = 0; mt < 4; ++mt)
#pragma unroll
                for (int r = 0; r < 4; ++r)
                    red[w][mt * 16 + quad * 4 + r] = psum[mt][r];
        }
        __syncthreads();

        if (tid < ET) {
            int e = t * ET + tid;
            if (e < NEDGES) {
                float s = 0.f;
#pragma unroll
                for (int i = 0; i < 8; ++i) s += red[i][tid];
                out[(size_t)c * NEDGES + e] = s;
            }
        }
        // no tail barrier needed: next tile's stage barrier orders the
        // red[] read (above) against the next epilogue's red[] write.
    };

    int t = t0;
    while (true) {
        body(t, ipk1, ipk0);            // parity 0: use t+NBX idx from ipk1
        t += NBX; if (t >= NT) break;
        body(t, ipk0, ipk1);            // parity 1
        t += NBX; if (t >= NT) break;
    }
}

extern "C" void kernel_launch(void* const* d_in, const int* in_sizes, int n_in,
                              void* d_out, int out_size, void* d_ws, size_t ws_size,
                              hipStream_t stream) {
    const float* hmat  = (const float*)d_in[0];
    const int*   src   = (const int*)d_in[1];
    const int*   dst   = (const int*)d_in[2];
    const float* RW    = (const float*)d_in[3];
    const float* dside = (const float*)d_in[4];
    const float* Wrel  = (const float*)d_in[5];
    const float* brel  = (const float*)d_in[6];
    float* out = (float*)d_out;

    // Workspace: Bh (512 KB) | Bl (512 KB) | H16 (51.2 MB)
    const size_t nB = (size_t)NCH * DIM * DIM;   // fp16 per table
    _Float16* Bh  = (_Float16*)d_ws;
    _Float16* Bl  = Bh + nB;
    _Float16* H16 = Bl + nB;

    prep_fused<<<dim3(128 + CONVB), dim3(256), 0, stream>>>(
        RW, dside, Wrel, hmat, Bh, Bl, H16);

    dim3 grid(NBX, NCH);
    edge_kernel<<<grid, dim3(512), 0, stream>>>(H16, src, dst, brel, Bh, Bl, out);
}

// Round 4
// 299.566 us; speedup vs baseline: 1.1754x; 1.0040x over previous
//
#include <hip/hip_runtime.h>
#include <stdint.h>

#define NNODES 100000
#define NEDGES 100000
#define DIM    256
#define NCH    4          // 2 side + 2 rel
#define ET     64         // edges per tile
#define NT     1563       // ceil(NEDGES / ET)
#define NBX    64         // blocks per channel; each block strides tiles by NBX
#define RSF    264        // fp16 per staged row (256 + 8 pad -> conflict-benign)
#define CONVB  2048       // grid-stride conversion blocks

typedef _Float16 f16x8 __attribute__((ext_vector_type(8)));
typedef _Float16 f16x4 __attribute__((ext_vector_type(4)));
typedef float f32x4  __attribute__((ext_vector_type(4)));

// ---------------------------------------------------------------------------
// Fused prep (single launch): B tables (hi/lo fp16, MFMA B-fragment order)
// + h f32 -> fp16 conversion. Unchanged (residue total-edge is invariant
// across 3 prep variants -> not a lever).
// ---------------------------------------------------------------------------
__global__ void prep_fused(const float* __restrict__ RW,
                           const float* __restrict__ dside,
                           const float* __restrict__ Wrel,
                           const float* __restrict__ h,
                           _Float16* __restrict__ Bh, _Float16* __restrict__ Bl,
                           _Float16* __restrict__ H16) {
    if (blockIdx.x < 128) {
        int t = blockIdx.x * blockDim.x + threadIdx.x;   // < 32768
        int lane = t & 63;
        int ft   = (t >> 6) & 15;
        int kc   = (t >> 10) & 7;
        int c    = t >> 13;
        int quad = lane >> 4, col = lane & 15;
        int f     = ft * 16 + col;
        int kbase = kc * 32 + quad * 8;

        f16x8 vh, vl;
#pragma unroll
        for (int j = 0; j < 8; ++j) {
            int k = kbase + j;
            float val;
            if (c < 2) {
                val = dside[c * DIM + f] * RW[f * DIM + k] * dside[c * DIM + k];
            } else {
                val = Wrel[(size_t)(c - 2) * DIM * DIM + f * DIM + k];
            }
            _Float16 hi = (_Float16)val;
            vh[j] = hi;
            vl[j] = (_Float16)(val - (float)hi);
        }
        ((f16x8*)Bh)[t] = vh;
        ((f16x8*)Bl)[t] = vl;
    } else {
        const int total4 = NNODES * DIM / 4;   // 6.4e6 f32x4 chunks
        const int stride = CONVB * 256;
        int i = (blockIdx.x - 128) * 256 + (int)threadIdx.x;
        const f32x4* s4 = (const f32x4*)h;
        f16x4* d4 = (f16x4*)H16;
        for (; i + stride < total4; i += 2 * stride) {
            f32x4 a = s4[i];
            f32x4 b = s4[i + stride];
            f16x4 oa, ob;
#pragma unroll
            for (int j = 0; j < 4; ++j) { oa[j] = (_Float16)a[j]; ob[j] = (_Float16)b[j]; }
            d4[i] = oa; d4[i + stride] = ob;
        }
        if (i < total4) {
            f32x4 a = s4[i];
            f16x4 o;
#pragma unroll
            for (int j = 0; j < 4; ++j) o[j] = (_Float16)a[j];
            d4[i] = o;
        }
    }
}

// ---------------------------------------------------------------------------
// Edge kernel v5 = v4 with the VGPR cap actually lifted.
//  ROUND-3 LESSON: __launch_bounds__(512,2) acted as min-BLOCKS-per-CU
//  (CUDA semantics) -> 16 waves/CU -> 128-VGPR cap -> B (128 VGPR by
//  itself) could NOT stay register-resident; compiler re-loaded B from L2
//  inside the K-loop -> vmcnt stalls -> MfmaUtil stuck at 28%.
//  Fix: __launch_bounds__(512,1): 1 block/CU, 8 waves, 256-VGPR cap.
//  B (32 x f16x8 = 128 VGPR) + acc(32) + pA/pV(32) + A(16) + misc ~ 240.
//  K-loop is then pure LDS+MFMA, no global ops, no vmcnt waits.
//  Also: Bh/Bl MFMA passes split per mt so dependent same-acc pairs have
//  4 independent MFMAs between them.
// ---------------------------------------------------------------------------
__global__ __launch_bounds__(512, 1)
void edge_kernel(const _Float16* __restrict__ H16,
                 const int* __restrict__ src_idx,
                 const int* __restrict__ dst_idx,
                 const float* __restrict__ brel,
                 const _Float16* __restrict__ Bh_sw,
                 const _Float16* __restrict__ Bl_sw,
                 float* __restrict__ out) {
    const int c    = blockIdx.y;
    const int tid  = threadIdx.x;
    const int w    = tid >> 6;          // 0..7
    const int lane = tid & 63;
    const int quad = lane >> 4, col = lane & 15;

    __shared__ __align__(16) _Float16 s_a[ET * RSF];   // 33,792 B
    __shared__ __align__(16) _Float16 s_v[ET * RSF];   // 33,792 B
    __shared__ float red[8][ET];                       // 2 KB

    // ---- B registers: wave w holds ft = {2w, 2w+1}, all kc, hi+lo ----
    f16x8 Bh_r[8][2], Bl_r[8][2];
    {
        const f16x8* bh = (const f16x8*)Bh_sw;
        const f16x8* bl = (const f16x8*)Bl_sw;
#pragma unroll
        for (int kc = 0; kc < 8; ++kc)
#pragma unroll
            for (int ftl = 0; ftl < 2; ++ftl) {
                int o = ((c * 8 + kc) * 16 + (w * 2 + ftl)) * 64 + lane;
                Bh_r[kc][ftl] = bh[o];
                Bl_r[kc][ftl] = bl[o];
            }
    }
    float bias[2];
#pragma unroll
    for (int ftl = 0; ftl < 2; ++ftl) {
        int f = (w * 2 + ftl) * 16 + col;
        bias[ftl] = (c >= 2) ? brel[(size_t)(c - 2) * DIM + f] : 0.f;
    }

    // Lane-packed index loads: lanes 0..7 -> src idx of rows w*8+0..7,
    // lanes 8..15 -> dst idx (pattern repeats harmlessly for lanes >= 16).
    const int  j8   = lane & 7;
    const bool isV  = (lane & 8) != 0;
    const int* ibase = (isV ? dst_idx : src_idx) + (size_t)c * NEDGES;

    auto loadpack = [&](int t) -> int {
        int e = t * ET + w * 8 + j8;
        if (e >= NEDGES) e = NEDGES - 1;
        return ibase[e];
    };

    // ---- Prologue: gather tile t0 rows; preload idx pack for t0+NBX ----
    const int t0 = blockIdx.x;
    f16x4 pA[8], pV[8];
    {
        int ip = loadpack(t0);
#pragma unroll
        for (int i = 0; i < 8; ++i) {
            int ia = __shfl(ip, i, 64);
            int iv = __shfl(ip, 8 + i, 64);
            pA[i] = *(const f16x4*)(H16 + (size_t)ia * DIM + lane * 4);
            pV[i] = *(const f16x4*)(H16 + (size_t)iv * DIM + lane * 4);
        }
    }
    int ipk0 = 0, ipk1 = 0;
    if (t0 + NBX < NT) ipk1 = loadpack(t0 + NBX);

    // ---- Tile body (ipkUse = idx for t+NBX, ipkLoad gets t+2*NBX) ----
    auto body = [&](int t, int& ipkUse, int& ipkLoad) {
        // stage tile t rows (gathered during previous tile)
#pragma unroll
        for (int i = 0; i < 8; ++i) {
            int lr = w * 8 + i;
            *(f16x4*)&s_a[lr * RSF + lane * 4] = pA[i];
            *(f16x4*)&s_v[lr * RSF + lane * 4] = pV[i];
        }
        __syncthreads();

        // issue idx loads 2 tiles ahead, row gathers 1 tile ahead (T14)
        if (t + 2 * NBX < NT) ipkLoad = loadpack(t + 2 * NBX);
        if (t + NBX < NT) {
#pragma unroll
            for (int i = 0; i < 8; ++i) {
                int ia = __shfl(ipkUse, i, 64);
                int iv = __shfl(ipkUse, 8 + i, 64);
                pA[i] = *(const f16x4*)(H16 + (size_t)ia * DIM + lane * 4);
                pV[i] = *(const f16x4*)(H16 + (size_t)iv * DIM + lane * 4);
            }
        }

        // K-loop: A from LDS, B from registers, 2-term f16 MFMA
        f32x4 acc[4][2];
#pragma unroll
        for (int mt = 0; mt < 4; ++mt)
#pragma unroll
            for (int ftl = 0; ftl < 2; ++ftl) acc[mt][ftl] = (f32x4){0.f, 0.f, 0.f, 0.f};

#pragma unroll
        for (int kc = 0; kc < 8; ++kc) {
            f16x8 A[4];
#pragma unroll
            for (int mt = 0; mt < 4; ++mt)
                A[mt] = *(const f16x8*)&s_a[(mt * 16 + col) * RSF + kc * 32 + quad * 8];
#pragma unroll
            for (int ftl = 0; ftl < 2; ++ftl) {
#pragma unroll
                for (int mt = 0; mt < 4; ++mt)
                    acc[mt][ftl] = __builtin_amdgcn_mfma_f32_16x16x32_f16(A[mt], Bh_r[kc][ftl], acc[mt][ftl], 0, 0, 0);
#pragma unroll
                for (int mt = 0; mt < 4; ++mt)
                    acc[mt][ftl] = __builtin_amdgcn_mfma_f32_16x16x32_f16(A[mt], Bl_r[kc][ftl], acc[mt][ftl], 0, 0, 0);
            }
        }

        // Epilogue: score_e = sum_f (C[e][f] + bias[f]) * V[e][f]
        float psum[4][4];
#pragma unroll
        for (int mt = 0; mt < 4; ++mt) {
#pragma unroll
            for (int r = 0; r < 4; ++r) {
                int el = mt * 16 + quad * 4 + r;
                float s = 0.f;
#pragma unroll
                for (int ftl = 0; ftl < 2; ++ftl) {
                    int f = (w * 2 + ftl) * 16 + col;
                    float v = (float)s_v[el * RSF + f];
                    s += (acc[mt][ftl][r] + bias[ftl]) * v;
                }
                psum[mt][r] = s;
            }
        }
#pragma unroll
        for (int off = 1; off < 16; off <<= 1) {
#pragma unroll
            for (int mt = 0; mt < 4; ++mt)
#pragma unroll
                for (int r = 0; r < 4; ++r)
                    psum[mt][r] += __shfl_xor(psum[mt][r], off, 64);
        }
        if (col == 0) {
#pragma unroll
            for (int mt = 0; mt < 4; ++mt)
#pragma unroll
                for (int r = 0; r < 4; ++r)
                    red[w][mt * 16 + quad * 4 + r] = psum[mt][r];
        }
        __syncthreads();

        if (tid < ET) {
            int e = t * ET + tid;
            if (e < NEDGES) {
                float s = 0.f;
#pragma unroll
                for (int i = 0; i < 8; ++i) s += red[i][tid];
                out[(size_t)c * NEDGES + e] = s;
            }
        }
        // no tail barrier: next tile's stage barrier orders red[] reads
        // against the next epilogue's red[] writes (s_a/s_v are distinct).
    };

    int t = t0;
    while (true) {
        body(t, ipk1, ipk0);            // parity 0: use t+NBX idx from ipk1
        t += NBX; if (t >= NT) break;
        body(t, ipk0, ipk1);            // parity 1
        t += NBX; if (t >= NT) break;
    }
}

extern "C" void kernel_launch(void* const* d_in, const int* in_sizes, int n_in,
                              void* d_out, int out_size, void* d_ws, size_t ws_size,
                              hipStream_t stream) {
    const float* hmat  = (const float*)d_in[0];
    const int*   src   = (const int*)d_in[1];
    const int*   dst   = (const int*)d_in[2];
    const float* RW    = (const float*)d_in[3];
    const float* dside = (const float*)d_in[4];
    const float* Wrel  = (const float*)d_in[5];
    const float* brel  = (const float*)d_in[6];
    float* out = (float*)d_out;

    // Workspace: Bh (512 KB) | Bl (512 KB) | H16 (51.2 MB)
    const size_t nB = (size_t)NCH * DIM * DIM;   // fp16 per table
    _Float16* Bh  = (_Float16*)d_ws;
    _Float16* Bl  = Bh + nB;
    _Float16* H16 = Bl + nB;

    prep_fused<<<dim3(128 + CONVB), dim3(256), 0, stream>>>(
        RW, dside, Wrel, hmat, Bh, Bl, H16);

    dim3 grid(NBX, NCH);
    edge_kernel<<<grid, dim3(512), 0, stream>>>(H16, src, dst, brel, Bh, Bl, out);
}

// Round 6
// 294.207 us; speedup vs baseline: 1.1968x; 1.0182x over previous
//
#include <hip/hip_runtime.h>
#include <stdint.h>

#define NNODES 100000
#define NEDGES 100000
#define DIM    256
#define NCH    4          // 2 side + 2 rel
#define ET     64         // edges per tile
#define NT     1563       // ceil(NEDGES / ET)
#define NBX    64         // blocks per channel; each block strides tiles by NBX
#define RSF    264        // fp16 per staged row (256 + 8 pad -> conflict-benign)
#define CONVB  2048       // grid-stride conversion blocks

typedef _Float16 f16x8 __attribute__((ext_vector_type(8)));
typedef _Float16 f16x4 __attribute__((ext_vector_type(4)));
typedef float f32x4  __attribute__((ext_vector_type(4)));

// ---------------------------------------------------------------------------
// Fused prep (single launch): B tables (hi/lo fp16, MFMA B-fragment order)
// + h f32 -> fp16 conversion. Unchanged (residue total-edge is invariant
// across 3 prep variants -> not a lever).
// ---------------------------------------------------------------------------
__global__ void prep_fused(const float* __restrict__ RW,
                           const float* __restrict__ dside,
                           const float* __restrict__ Wrel,
                           const float* __restrict__ h,
                           _Float16* __restrict__ Bh, _Float16* __restrict__ Bl,
                           _Float16* __restrict__ H16) {
    if (blockIdx.x < 128) {
        int t = blockIdx.x * blockDim.x + threadIdx.x;   // < 32768
        int lane = t & 63;
        int ft   = (t >> 6) & 15;
        int kc   = (t >> 10) & 7;
        int c    = t >> 13;
        int quad = lane >> 4, col = lane & 15;
        int f     = ft * 16 + col;
        int kbase = kc * 32 + quad * 8;

        f16x8 vh, vl;
#pragma unroll
        for (int j = 0; j < 8; ++j) {
            int k = kbase + j;
            float val;
            if (c < 2) {
                val = dside[c * DIM + f] * RW[f * DIM + k] * dside[c * DIM + k];
            } else {
                val = Wrel[(size_t)(c - 2) * DIM * DIM + f * DIM + k];
            }
            _Float16 hi = (_Float16)val;
            vh[j] = hi;
            vl[j] = (_Float16)(val - (float)hi);
        }
        ((f16x8*)Bh)[t] = vh;
        ((f16x8*)Bl)[t] = vl;
    } else {
        const int total4 = NNODES * DIM / 4;   // 6.4e6 f32x4 chunks
        const int stride = CONVB * 256;
        int i = (blockIdx.x - 128) * 256 + (int)threadIdx.x;
        const f32x4* s4 = (const f32x4*)h;
        f16x4* d4 = (f16x4*)H16;
        for (; i + stride < total4; i += 2 * stride) {
            f32x4 a = s4[i];
            f32x4 b = s4[i + stride];
            f16x4 oa, ob;
#pragma unroll
            for (int j = 0; j < 4; ++j) { oa[j] = (_Float16)a[j]; ob[j] = (_Float16)b[j]; }
            d4[i] = oa; d4[i + stride] = ob;
        }
        if (i < total4) {
            f32x4 a = s4[i];
            f16x4 o;
#pragma unroll
            for (int j = 0; j < 4; ++j) o[j] = (_Float16)a[j];
            d4[i] = o;
        }
    }
}

// ---------------------------------------------------------------------------
// Edge kernel v6 (retry — round-5 bench died to infra, not the kernel):
// FORCED register residency for B.
//  ROUND-4 LESSON: VGPR_Count stayed 128 even with launch_bounds(512,1) --
//  the allocator CHOSE 128 and rematerialized (re-loaded) the B fragments
//  from L2 inside the tile loop (legal: the underlying memory is const).
//  MfmaUtil 30% = 44us busy vs 146us total: the other 70% is the vmcnt
//  stalls of those re-loads.
//  Fix: pin each B fragment with an opaque empty inline-asm redefinition
//  ("+v"). The asm result cannot be rematerialized, so the values must
//  stay in VGPRs across the whole tile loop (~240 live VGPR < 256 budget
//  at 1 block/CU). The K-loop then has ZERO global loads.
// ---------------------------------------------------------------------------
__global__ __launch_bounds__(512, 1)
void edge_kernel(const _Float16* __restrict__ H16,
                 const int* __restrict__ src_idx,
                 const int* __restrict__ dst_idx,
                 const float* __restrict__ brel,
                 const _Float16* __restrict__ Bh_sw,
                 const _Float16* __restrict__ Bl_sw,
                 float* __restrict__ out) {
    const int c    = blockIdx.y;
    const int tid  = threadIdx.x;
    const int w    = tid >> 6;          // 0..7
    const int lane = tid & 63;
    const int quad = lane >> 4, col = lane & 15;

    __shared__ __align__(16) _Float16 s_a[ET * RSF];   // 33,792 B
    __shared__ __align__(16) _Float16 s_v[ET * RSF];   // 33,792 B
    __shared__ float red[8][ET];                       // 2 KB

    // ---- B registers: wave w holds ft = {2w, 2w+1}, all kc, hi+lo ----
    f16x8 Bh_r[8][2], Bl_r[8][2];
    {
        const f16x8* bh = (const f16x8*)Bh_sw;
        const f16x8* bl = (const f16x8*)Bl_sw;
#pragma unroll
        for (int kc = 0; kc < 8; ++kc)
#pragma unroll
            for (int ftl = 0; ftl < 2; ++ftl) {
                int o = ((c * 8 + kc) * 16 + (w * 2 + ftl)) * 64 + lane;
                Bh_r[kc][ftl] = bh[o];
                Bl_r[kc][ftl] = bl[o];
            }
    }
    // Pin B in registers: opaque redefinition -> cannot be rematerialized,
    // so the allocator must keep these 128 VGPRs live across the tile loop.
#pragma unroll
    for (int kc = 0; kc < 8; ++kc)
#pragma unroll
        for (int ftl = 0; ftl < 2; ++ftl)
            asm volatile("" : "+v"(Bh_r[kc][ftl]), "+v"(Bl_r[kc][ftl]));

    float bias[2];
#pragma unroll
    for (int ftl = 0; ftl < 2; ++ftl) {
        int f = (w * 2 + ftl) * 16 + col;
        bias[ftl] = (c >= 2) ? brel[(size_t)(c - 2) * DIM + f] : 0.f;
    }

    // Lane-packed index loads: lanes 0..7 -> src idx of rows w*8+0..7,
    // lanes 8..15 -> dst idx (pattern repeats harmlessly for lanes >= 16).
    const int  j8   = lane & 7;
    const bool isV  = (lane & 8) != 0;
    const int* ibase = (isV ? dst_idx : src_idx) + (size_t)c * NEDGES;

    auto loadpack = [&](int t) -> int {
        int e = t * ET + w * 8 + j8;
        if (e >= NEDGES) e = NEDGES - 1;
        return ibase[e];
    };

    // ---- Prologue: gather tile t0 rows; preload idx pack for t0+NBX ----
    const int t0 = blockIdx.x;
    f16x4 pA[8], pV[8];
    {
        int ip = loadpack(t0);
#pragma unroll
        for (int i = 0; i < 8; ++i) {
            int ia = __shfl(ip, i, 64);
            int iv = __shfl(ip, 8 + i, 64);
            pA[i] = *(const f16x4*)(H16 + (size_t)ia * DIM + lane * 4);
            pV[i] = *(const f16x4*)(H16 + (size_t)iv * DIM + lane * 4);
        }
    }
    int ipk0 = 0, ipk1 = 0;
    if (t0 + NBX < NT) ipk1 = loadpack(t0 + NBX);

    // ---- Tile body (ipkUse = idx for t+NBX, ipkLoad gets t+2*NBX) ----
    auto body = [&](int t, int& ipkUse, int& ipkLoad) {
        // stage tile t rows (gathered during previous tile)
#pragma unroll
        for (int i = 0; i < 8; ++i) {
            int lr = w * 8 + i;
            *(f16x4*)&s_a[lr * RSF + lane * 4] = pA[i];
            *(f16x4*)&s_v[lr * RSF + lane * 4] = pV[i];
        }
        __syncthreads();

        // issue idx loads 2 tiles ahead, row gathers 1 tile ahead (T14)
        if (t + 2 * NBX < NT) ipkLoad = loadpack(t + 2 * NBX);
        if (t + NBX < NT) {
#pragma unroll
            for (int i = 0; i < 8; ++i) {
                int ia = __shfl(ipkUse, i, 64);
                int iv = __shfl(ipkUse, 8 + i, 64);
                pA[i] = *(const f16x4*)(H16 + (size_t)ia * DIM + lane * 4);
                pV[i] = *(const f16x4*)(H16 + (size_t)iv * DIM + lane * 4);
            }
        }

        // K-loop: A from LDS, B from registers, 2-term f16 MFMA.
        // No global ops in here at all (B pinned above).
        f32x4 acc[4][2];
#pragma unroll
        for (int mt = 0; mt < 4; ++mt)
#pragma unroll
            for (int ftl = 0; ftl < 2; ++ftl) acc[mt][ftl] = (f32x4){0.f, 0.f, 0.f, 0.f};

#pragma unroll
        for (int kc = 0; kc < 8; ++kc) {
            f16x8 A[4];
#pragma unroll
            for (int mt = 0; mt < 4; ++mt)
                A[mt] = *(const f16x8*)&s_a[(mt * 16 + col) * RSF + kc * 32 + quad * 8];
#pragma unroll
            for (int ftl = 0; ftl < 2; ++ftl) {
#pragma unroll
                for (int mt = 0; mt < 4; ++mt)
                    acc[mt][ftl] = __builtin_amdgcn_mfma_f32_16x16x32_f16(A[mt], Bh_r[kc][ftl], acc[mt][ftl], 0, 0, 0);
#pragma unroll
                for (int mt = 0; mt < 4; ++mt)
                    acc[mt][ftl] = __builtin_amdgcn_mfma_f32_16x16x32_f16(A[mt], Bl_r[kc][ftl], acc[mt][ftl], 0, 0, 0);
            }
        }

        // Epilogue: score_e = sum_f (C[e][f] + bias[f]) * V[e][f]
        float psum[4][4];
#pragma unroll
        for (int mt = 0; mt < 4; ++mt) {
#pragma unroll
            for (int r = 0; r < 4; ++r) {
                int el = mt * 16 + quad * 4 + r;
                float s = 0.f;
#pragma unroll
                for (int ftl = 0; ftl < 2; ++ftl) {
                    int f = (w * 2 + ftl) * 16 + col;
                    float v = (float)s_v[el * RSF + f];
                    s += (acc[mt][ftl][r] + bias[ftl]) * v;
                }
                psum[mt][r] = s;
            }
        }
#pragma unroll
        for (int off = 1; off < 16; off <<= 1) {
#pragma unroll
            for (int mt = 0; mt < 4; ++mt)
#pragma unroll
                for (int r = 0; r < 4; ++r)
                    psum[mt][r] += __shfl_xor(psum[mt][r], off, 64);
        }
        if (col == 0) {
#pragma unroll
            for (int mt = 0; mt < 4; ++mt)
#pragma unroll
                for (int r = 0; r < 4; ++r)
                    red[w][mt * 16 + quad * 4 + r] = psum[mt][r];
        }
        __syncthreads();

        if (tid < ET) {
            int e = t * ET + tid;
            if (e < NEDGES) {
                float s = 0.f;
#pragma unroll
                for (int i = 0; i < 8; ++i) s += red[i][tid];
                out[(size_t)c * NEDGES + e] = s;
            }
        }
        // no tail barrier: next tile's stage barrier orders red[] reads
        // against the next epilogue's red[] writes (s_a/s_v are distinct).
    };

    int t = t0;
    while (true) {
        body(t, ipk1, ipk0);            // parity 0: use t+NBX idx from ipk1
        t += NBX; if (t >= NT) break;
        body(t, ipk0, ipk1);            // parity 1
        t += NBX; if (t >= NT) break;
    }
}

extern "C" void kernel_launch(void* const* d_in, const int* in_sizes, int n_in,
                              void* d_out, int out_size, void* d_ws, size_t ws_size,
                              hipStream_t stream) {
    const float* hmat  = (const float*)d_in[0];
    const int*   src   = (const int*)d_in[1];
    const int*   dst   = (const int*)d_in[2];
    const float* RW    = (const float*)d_in[3];
    const float* dside = (const float*)d_in[4];
    const float* Wrel  = (const float*)d_in[5];
    const float* brel  = (const float*)d_in[6];
    float* out = (float*)d_out;

    // Workspace: Bh (512 KB) | Bl (512 KB) | H16 (51.2 MB)
    const size_t nB = (size_t)NCH * DIM * DIM;   // fp16 per table
    _Float16* Bh  = (_Float16*)d_ws;
    _Float16* Bl  = Bh + nB;
    _Float16* H16 = Bl + nB;

    prep_fused<<<dim3(128 + CONVB), dim3(256), 0, stream>>>(
        RW, dside, Wrel, hmat, Bh, Bl, H16);

    dim3 grid(NBX, NCH);
    edge_kernel<<<grid, dim3(512), 0, stream>>>(H16, src, dst, brel, Bh, Bl, out);
}

// Round 7
// 277.657 us; speedup vs baseline: 1.2682x; 1.0596x over previous
//
#include <hip/hip_runtime.h>
#include <stdint.h>

#define NNODES 100000
#define NEDGES 100000
#define DIM    256
#define NCH    4          // 2 side + 2 rel
#define ET     64         // edges per tile
#define NT     1563       // ceil(NEDGES / ET)
#define NBX    64         // blocks per channel; each block strides tiles by NBX
#define RSF    264        // fp16 per staged row (256 + 8 pad -> conflict-benign)
#define CONVB  2048       // grid-stride conversion blocks

typedef _Float16 f16x8 __attribute__((ext_vector_type(8)));
typedef _Float16 f16x4 __attribute__((ext_vector_type(4)));
typedef float f32x4  __attribute__((ext_vector_type(4)));

// ---------------------------------------------------------------------------
// Fused prep (single launch): B tables (hi/lo fp16, MFMA B-fragment order)
// + h f32 -> fp16 conversion. Unchanged (not a lever; residue is fixed
// overhead, invariant across 3 prep variants).
// ---------------------------------------------------------------------------
__global__ void prep_fused(const float* __restrict__ RW,
                           const float* __restrict__ dside,
                           const float* __restrict__ Wrel,
                           const float* __restrict__ h,
                           _Float16* __restrict__ Bh, _Float16* __restrict__ Bl,
                           _Float16* __restrict__ H16) {
    if (blockIdx.x < 128) {
        int t = blockIdx.x * blockDim.x + threadIdx.x;   // < 32768
        int lane = t & 63;
        int ft   = (t >> 6) & 15;
        int kc   = (t >> 10) & 7;
        int c    = t >> 13;
        int quad = lane >> 4, col = lane & 15;
        int f     = ft * 16 + col;
        int kbase = kc * 32 + quad * 8;

        f16x8 vh, vl;
#pragma unroll
        for (int j = 0; j < 8; ++j) {
            int k = kbase + j;
            float val;
            if (c < 2) {
                val = dside[c * DIM + f] * RW[f * DIM + k] * dside[c * DIM + k];
            } else {
                val = Wrel[(size_t)(c - 2) * DIM * DIM + f * DIM + k];
            }
            _Float16 hi = (_Float16)val;
            vh[j] = hi;
            vl[j] = (_Float16)(val - (float)hi);
        }
        ((f16x8*)Bh)[t] = vh;
        ((f16x8*)Bl)[t] = vl;
    } else {
        const int total4 = NNODES * DIM / 4;   // 6.4e6 f32x4 chunks
        const int stride = CONVB * 256;
        int i = (blockIdx.x - 128) * 256 + (int)threadIdx.x;
        const f32x4* s4 = (const f32x4*)h;
        f16x4* d4 = (f16x4*)H16;
        for (; i + stride < total4; i += 2 * stride) {
            f32x4 a = s4[i];
            f32x4 b = s4[i + stride];
            f16x4 oa, ob;
#pragma unroll
            for (int j = 0; j < 4; ++j) { oa[j] = (_Float16)a[j]; ob[j] = (_Float16)b[j]; }
            d4[i] = oa; d4[i + stride] = ob;
        }
        if (i < total4) {
            f32x4 a = s4[i];
            f16x4 o;
#pragma unroll
            for (int j = 0; j < 4; ++j) o[j] = (_Float16)a[j];
            d4[i] = o;
        }
    }
}

// ---------------------------------------------------------------------------
// 16-lane-row sum reduction entirely on the VALU via DPP (no DS-pipe ops).
// Steps: xor1 = quad_perm(1,0,3,2)=0xB1; xor2 = quad_perm(2,3,0,1)=0x4E;
// 8-group pairing = row_half_mirror (0x141); 16-group pairing = row_mirror
// (0x140). After 4 add-steps every lane in the 16-group holds the 16-sum.
// ---------------------------------------------------------------------------
__device__ __forceinline__ float dpp_reduce16(float s) {
    union { float f; int i; } u, v;
    u.f = s; v.i = __builtin_amdgcn_update_dpp(0, u.i, 0xB1,  0xF, 0xF, true); s += v.f;
    u.f = s; v.i = __builtin_amdgcn_update_dpp(0, u.i, 0x4E,  0xF, 0xF, true); s += v.f;
    u.f = s; v.i = __builtin_amdgcn_update_dpp(0, u.i, 0x141, 0xF, 0xF, true); s += v.f;
    u.f = s; v.i = __builtin_amdgcn_update_dpp(0, u.i, 0x140, 0xF, 0xF, true); s += v.f;
    return s;
}

// ---------------------------------------------------------------------------
// Edge kernel v7 = v6 with the epilogue reduction moved DS -> VALU (DPP).
//  ROUND-6 LESSON: rounds 4 and 6 identical (147us, VGPR=128) => B was
//  ALREADY register-resident, in AGPRs (unified file: 128 VGPR + 128 AGPR
//  = full 256 budget). No K-loop global loads. DS-pipe accounting shows
//  the true bottleneck (~8300 cy/tile DS vs 4966 cy MFMA):
//    A ds_read_b128 ~3080 | shfl_xor tree ~3070 | V scalar reads ~1540.
//  This round removes the shuffle tree from the DS pipe via DPP.
// ---------------------------------------------------------------------------
__global__ __launch_bounds__(512, 1)
void edge_kernel(const _Float16* __restrict__ H16,
                 const int* __restrict__ src_idx,
                 const int* __restrict__ dst_idx,
                 const float* __restrict__ brel,
                 const _Float16* __restrict__ Bh_sw,
                 const _Float16* __restrict__ Bl_sw,
                 float* __restrict__ out) {
    const int c    = blockIdx.y;
    const int tid  = threadIdx.x;
    const int w    = tid >> 6;          // 0..7
    const int lane = tid & 63;
    const int quad = lane >> 4, col = lane & 15;

    __shared__ __align__(16) _Float16 s_a[ET * RSF];   // 33,792 B
    __shared__ __align__(16) _Float16 s_v[ET * RSF];   // 33,792 B
    __shared__ float red[8][ET];                       // 2 KB

    // ---- B registers: wave w holds ft = {2w, 2w+1}, all kc, hi+lo ----
    f16x8 Bh_r[8][2], Bl_r[8][2];
    {
        const f16x8* bh = (const f16x8*)Bh_sw;
        const f16x8* bl = (const f16x8*)Bl_sw;
#pragma unroll
        for (int kc = 0; kc < 8; ++kc)
#pragma unroll
            for (int ftl = 0; ftl < 2; ++ftl) {
                int o = ((c * 8 + kc) * 16 + (w * 2 + ftl)) * 64 + lane;
                Bh_r[kc][ftl] = bh[o];
                Bl_r[kc][ftl] = bl[o];
            }
    }
    // Pin B (kept from v6; harmless — B lives in AGPRs either way).
#pragma unroll
    for (int kc = 0; kc < 8; ++kc)
#pragma unroll
        for (int ftl = 0; ftl < 2; ++ftl)
            asm volatile("" : "+v"(Bh_r[kc][ftl]), "+v"(Bl_r[kc][ftl]));

    float bias[2];
#pragma unroll
    for (int ftl = 0; ftl < 2; ++ftl) {
        int f = (w * 2 + ftl) * 16 + col;
        bias[ftl] = (c >= 2) ? brel[(size_t)(c - 2) * DIM + f] : 0.f;
    }

    // Lane-packed index loads: lanes 0..7 -> src idx of rows w*8+0..7,
    // lanes 8..15 -> dst idx (pattern repeats harmlessly for lanes >= 16).
    const int  j8   = lane & 7;
    const bool isV  = (lane & 8) != 0;
    const int* ibase = (isV ? dst_idx : src_idx) + (size_t)c * NEDGES;

    auto loadpack = [&](int t) -> int {
        int e = t * ET + w * 8 + j8;
        if (e >= NEDGES) e = NEDGES - 1;
        return ibase[e];
    };

    // ---- Prologue: gather tile t0 rows; preload idx pack for t0+NBX ----
    const int t0 = blockIdx.x;
    f16x4 pA[8], pV[8];
    {
        int ip = loadpack(t0);
#pragma unroll
        for (int i = 0; i < 8; ++i) {
            int ia = __shfl(ip, i, 64);
            int iv = __shfl(ip, 8 + i, 64);
            pA[i] = *(const f16x4*)(H16 + (size_t)ia * DIM + lane * 4);
            pV[i] = *(const f16x4*)(H16 + (size_t)iv * DIM + lane * 4);
        }
    }
    int ipk0 = 0, ipk1 = 0;
    if (t0 + NBX < NT) ipk1 = loadpack(t0 + NBX);

    // ---- Tile body (ipkUse = idx for t+NBX, ipkLoad gets t+2*NBX) ----
    auto body = [&](int t, int& ipkUse, int& ipkLoad) {
        // stage tile t rows (gathered during previous tile)
#pragma unroll
        for (int i = 0; i < 8; ++i) {
            int lr = w * 8 + i;
            *(f16x4*)&s_a[lr * RSF + lane * 4] = pA[i];
            *(f16x4*)&s_v[lr * RSF + lane * 4] = pV[i];
        }
        __syncthreads();

        // issue idx loads 2 tiles ahead, row gathers 1 tile ahead (T14)
        if (t + 2 * NBX < NT) ipkLoad = loadpack(t + 2 * NBX);
        if (t + NBX < NT) {
#pragma unroll
            for (int i = 0; i < 8; ++i) {
                int ia = __shfl(ipkUse, i, 64);
                int iv = __shfl(ipkUse, 8 + i, 64);
                pA[i] = *(const f16x4*)(H16 + (size_t)ia * DIM + lane * 4);
                pV[i] = *(const f16x4*)(H16 + (size_t)iv * DIM + lane * 4);
            }
        }

        // K-loop: A from LDS, B from registers (AGPR-resident), 2-term MFMA.
        f32x4 acc[4][2];
#pragma unroll
        for (int mt = 0; mt < 4; ++mt)
#pragma unroll
            for (int ftl = 0; ftl < 2; ++ftl) acc[mt][ftl] = (f32x4){0.f, 0.f, 0.f, 0.f};

#pragma unroll
        for (int kc = 0; kc < 8; ++kc) {
            f16x8 A[4];
#pragma unroll
            for (int mt = 0; mt < 4; ++mt)
                A[mt] = *(const f16x8*)&s_a[(mt * 16 + col) * RSF + kc * 32 + quad * 8];
#pragma unroll
            for (int ftl = 0; ftl < 2; ++ftl) {
#pragma unroll
                for (int mt = 0; mt < 4; ++mt)
                    acc[mt][ftl] = __builtin_amdgcn_mfma_f32_16x16x32_f16(A[mt], Bh_r[kc][ftl], acc[mt][ftl], 0, 0, 0);
#pragma unroll
                for (int mt = 0; mt < 4; ++mt)
                    acc[mt][ftl] = __builtin_amdgcn_mfma_f32_16x16x32_f16(A[mt], Bl_r[kc][ftl], acc[mt][ftl], 0, 0, 0);
            }
        }

        // Epilogue: score_e = sum_f (C[e][f] + bias[f]) * V[e][f]
        // Reduction across the 16 f-columns now on the VALU pipe (DPP),
        // removing 64 DS ops/wave (~3070 cy/tile) from the DS pipe.
        float psum[4][4];
#pragma unroll
        for (int mt = 0; mt < 4; ++mt) {
#pragma unroll
            for (int r = 0; r < 4; ++r) {
                int el = mt * 16 + quad * 4 + r;
                float s = 0.f;
#pragma unroll
                for (int ftl = 0; ftl < 2; ++ftl) {
                    int f = (w * 2 + ftl) * 16 + col;
                    float v = (float)s_v[el * RSF + f];
                    s += (acc[mt][ftl][r] + bias[ftl]) * v;
                }
                psum[mt][r] = dpp_reduce16(s);
            }
        }
        if (col == 0) {
#pragma unroll
            for (int mt = 0; mt < 4; ++mt)
#pragma unroll
                for (int r = 0; r < 4; ++r)
                    red[w][mt * 16 + quad * 4 + r] = psum[mt][r];
        }
        __syncthreads();

        if (tid < ET) {
            int e = t * ET + tid;
            if (e < NEDGES) {
                float s = 0.f;
#pragma unroll
                for (int i = 0; i < 8; ++i) s += red[i][tid];
                out[(size_t)c * NEDGES + e] = s;
            }
        }
        // no tail barrier: next tile's stage barrier orders red[] reads
        // against the next epilogue's red[] writes (s_a/s_v are distinct).
    };

    int t = t0;
    while (true) {
        body(t, ipk1, ipk0);            // parity 0: use t+NBX idx from ipk1
        t += NBX; if (t >= NT) break;
        body(t, ipk0, ipk1);            // parity 1
        t += NBX; if (t >= NT) break;
    }
}

extern "C" void kernel_launch(void* const* d_in, const int* in_sizes, int n_in,
                              void* d_out, int out_size, void* d_ws, size_t ws_size,
                              hipStream_t stream) {
    const float* hmat  = (const float*)d_in[0];
    const int*   src   = (const int*)d_in[1];
    const int*   dst   = (const int*)d_in[2];
    const float* RW    = (const float*)d_in[3];
    const float* dside = (const float*)d_in[4];
    const float* Wrel  = (const float*)d_in[5];
    const float* brel  = (const float*)d_in[6];
    float* out = (float*)d_out;

    // Workspace: Bh (512 KB) | Bl (512 KB) | H16 (51.2 MB)
    const size_t nB = (size_t)NCH * DIM * DIM;   // fp16 per table
    _Float16* Bh  = (_Float16*)d_ws;
    _Float16* Bl  = Bh + nB;
    _Float16* H16 = Bl + nB;

    prep_fused<<<dim3(128 + CONVB), dim3(256), 0, stream>>>(
        RW, dside, Wrel, hmat, Bh, Bl, H16);

    dim3 grid(NBX, NCH);
    edge_kernel<<<grid, dim3(512), 0, stream>>>(H16, src, dst, brel, Bh, Bl, out);
}